// Round 1
// baseline (97.058 us; speedup 1.0000x reference)
//
#include <hip/hip_runtime.h>
#include <math.h>

#define NUM_MOE 64
#define DIM 64
#define WAVES_PER_BLOCK 4

__global__ __launch_bounds__(256, 4)
void moe_router_kernel(const float* __restrict__ x,
                       const float* __restrict__ W,
                       float* __restrict__ out,
                       int ntok) {
    const int lane = threadIdx.x & 63;
    const int wid  = threadIdx.x >> 6;
    // wave-uniform global wave id (forces scalar-ization of token addressing)
    int gwave  = __builtin_amdgcn_readfirstlane(blockIdx.x * WAVES_PER_BLOCK + wid);
    int nwaves = gridDim.x * WAVES_PER_BLOCK;

    // Each lane caches its expert's weight row: W[lane][0..63] -> 64 VGPRs.
    // 16 float4 loads, hits L1/L2 (W is 16 KB total), once per wave lifetime.
    float w[DIM];
    {
        const float4* wrow = reinterpret_cast<const float4*>(W + lane * DIM);
        #pragma unroll
        for (int k = 0; k < DIM / 4; ++k) {
            float4 v = wrow[k];
            w[4 * k + 0] = v.x; w[4 * k + 1] = v.y;
            w[4 * k + 2] = v.z; w[4 * k + 3] = v.w;
        }
    }

    for (int t = gwave; t < ntok; t += nwaves) {
        const float* xt = x + (size_t)t * DIM;   // wave-uniform -> s_load path

        // logit for expert `lane`: dot(x[t], W[lane])
        float acc = 0.0f;
        #pragma unroll
        for (int d = 0; d < DIM; ++d) {
            acc = fmaf(xt[d], w[d], acc);        // x from SGPR broadcast
        }

        // ---- wave softmax + exact top-2 (lane = expert) ----
        // full-butterfly max -> every lane has M (exact value, no truncation)
        float M = acc;
        #pragma unroll
        for (int off = 32; off >= 1; off >>= 1)
            M = fmaxf(M, __shfl_xor(M, off));
        unsigned long long b1 = __ballot(acc == M);
        int i1 = __ffsll(b1) - 1;                // lowest index: matches top_k tie-break

        float e = __builtin_expf(acc - M);       // e(i1) == 1
        float Z = e;
        #pragma unroll
        for (int off = 32; off >= 1; off >>= 1)
            Z += __shfl_xor(Z, off);

        // second max with lane i1 masked out
        float v2 = (lane == i1) ? -INFINITY : acc;
        float M2 = v2;
        #pragma unroll
        for (int off = 32; off >= 1; off >>= 1)
            M2 = fmaxf(M2, __shfl_xor(M2, off));
        unsigned long long b2 = __ballot(v2 == M2);
        int i2 = __ffsll(b2) - 1;

        float e2 = __shfl(e, i2);                // exp(l_i2 - M), uniform lane idx
        // p1 - p2 = (1 - e2)/Z ;  out[i1] = sigmoid(p1-p2), out[i2] = 1 - out[i1]
        float d12 = (1.0f - e2) / Z;
        float w1  = 1.0f / (1.0f + __builtin_expf(-d12));
        float w2  = 1.0f - w1;

        float outv = (lane == i1) ? w1 : ((lane == i2) ? w2 : 0.0f);
        out[(size_t)t * DIM + lane] = outv;      // coalesced 256 B per token
    }
}

extern "C" void kernel_launch(void* const* d_in, const int* in_sizes, int n_in,
                              void* d_out, int out_size, void* d_ws, size_t ws_size,
                              hipStream_t stream) {
    const float* x = (const float*)d_in[0];
    const float* W = (const float*)d_in[1];
    float* out = (float*)d_out;
    int ntok = in_sizes[0] / DIM;   // 32*8192 = 262144

    const int blocks = 2048;        // 8192 waves, 32 tokens/wave, 8 blocks/CU
    moe_router_kernel<<<blocks, 256, 0, stream>>>(x, W, out, ntok);
}